// Round 11
// baseline (183.506 us; speedup 1.0000x reference)
//
#include <hip/hip_runtime.h>

#define NN 10000
#define NE 160000
#define KD 1433
#define KP 1536    // padded K (zero-filled in Wb)
#define SK1 2      // split-K (partial buffers, no atomics)
#define KC 768     // K per block
#define KSTEP 64   // K per LDS stage
#define NST 12     // CHUNK/KSTEP

typedef unsigned short u16;
typedef __attribute__((ext_vector_type(4))) float f32x4;
typedef __attribute__((ext_vector_type(8))) short bf16x8;
typedef __attribute__((ext_vector_type(4), aligned(4))) float f32x4u;

__device__ __forceinline__ u16 f2bf(float f) {
    union { float f; unsigned u; } v; v.f = f;
    unsigned r = (v.u + 0x7FFF + ((v.u >> 16) & 1)) >> 16;
    return (u16)r;
}

// async global->LDS, 16B per lane: per-lane global src, wave-uniform LDS base (+lane*16)
__device__ __forceinline__ void gload16(const void* g, void* l) {
    __builtin_amdgcn_global_load_lds(
        (__attribute__((address_space(1))) void*)(void*)g,
        (__attribute__((address_space(3))) void*)l, 16, 0, 0);
}

// ---------- edge dtype detect ----------
__global__ __launch_bounds__(256) void detect_kernel(const int* __restrict__ e, int* __restrict__ flag) {
    __shared__ int nz;
    if (threadIdx.x == 0) nz = 0;
    __syncthreads();
    int cnt = 0;
    for (int i = threadIdx.x; i < 4000; i += 256)
        if (e[2 * i + 1] != 0) cnt++;
    if (cnt) atomicAdd(&nz, cnt);
    __syncthreads();
    if (threadIdx.x == 0) *flag = (nz == 0) ? 1 : 0;  // 1 => data is int64
}

// ---------- repack edges + int degree count ----------
__global__ __launch_bounds__(256) void repackdeg_kernel(const int* __restrict__ e, const int* __restrict__ flag,
                                                        int* __restrict__ srcI, int* __restrict__ dstI,
                                                        int* __restrict__ cnt) {
    int i = blockIdx.x * 256 + threadIdx.x;
    if (i >= NE) return;
    int s, d;
    if (*flag) {
        s = e[2 * i];
        d = e[2 * (NE + i)];
    } else {
        s = e[i];
        d = e[NE + i];
    }
    srcI[i] = s;
    dstI[i] = d;
    atomicAdd(&cnt[d], 1);
}

// ---------- single-block scan: rowptr/cursor from cnt; also deg_inv ----------
#define SCHUNK 40  // 256*40 = 10240 >= NN
__global__ __launch_bounds__(256) void scan_kernel(const int* __restrict__ cnt, int* __restrict__ rowptr,
                                                   int* __restrict__ cursor, float* __restrict__ deg_inv) {
    __shared__ int part[256];
    const int t = threadIdx.x;
    const int base = t * SCHUNK;
    int s = 0;
    for (int i = 0; i < SCHUNK; ++i) {
        int bi = base + i;
        s += (bi < NN) ? cnt[bi] : 0;
    }
    part[t] = s;
    __syncthreads();
    // Hillis-Steele inclusive scan over 256 partials
    for (int off = 1; off < 256; off <<= 1) {
        int u = (t >= off) ? part[t - off] : 0;
        __syncthreads();
        part[t] += u;
        __syncthreads();
    }
    int run = part[t] - s;  // exclusive start of this thread's chunk
    for (int i = 0; i < SCHUNK; ++i) {
        int bi = base + i;
        if (bi < NN) {
            rowptr[bi] = run;
            cursor[bi] = run;
            int c = cnt[bi];
            deg_inv[bi] = (c > 0) ? (1.0f / (float)c) : 0.f;
            run += c;
        }
    }
    if (t == 255) rowptr[NN] = part[255];
}

// ---------- scatter edges into CSR by dst ----------
__global__ __launch_bounds__(256) void scatter_kernel(const int* __restrict__ srcI, const int* __restrict__ dstI,
                                                      int* __restrict__ cursor, int* __restrict__ csr) {
    int i = blockIdx.x * 256 + threadIdx.x;
    if (i >= NE) return;
    int pos = atomicAdd(&cursor[dstI[i]], 1);
    csr[pos] = srcI[i];
}

// ---------- W1 -> bf16 (128 x KP, zero-padded) ----------
__global__ __launch_bounds__(256) void convw_kernel(const float* __restrict__ Wl, const float* __restrict__ Wr,
                                                    u16* __restrict__ Wb) {
    int gid = blockIdx.x * 256 + threadIdx.x;
    if (gid >= 128 * (KP / 8)) return;
    int r = gid / (KP / 8), k0 = (gid % (KP / 8)) * 8;
    const float* srcw = (r < 64) ? (Wl + r * KD) : (Wr + (r - 64) * KD);
    u16 u[8];
    #pragma unroll
    for (int i = 0; i < 8; ++i) {
        int k = k0 + i;
        u[i] = (k < KD) ? f2bf(srcw[k]) : (u16)0;
    }
    *(uint4*)&Wb[r * KP + k0] = *(const uint4*)u;
}

// ---------- layer-1 MFMA GEMM v5: global_load_lds staging, pre-swizzled sources ----------
__global__ __launch_bounds__(256) void mm1_mfma(const float* __restrict__ x, const u16* __restrict__ Wb,
                                                float* __restrict__ yp) {
    __shared__ float AT[2][2048];   // 8KB/buf: 8 pages x (4 rows x 64 floats)
    __shared__ u16  WT[2][8192];    // 16KB/buf: 16 pages x (8 rows x 64 bf16)
    const int t = threadIdx.x;
    const int w = t >> 6, lane = t & 63;
    const int n0 = blockIdx.x * 32;
    const int kc0 = blockIdx.y * KC;

    const int rowinA = lane >> 4;
    const int cA = lane & 15;
    size_t aoff[2];
    #pragma unroll
    for (int ii = 0; ii < 2; ++ii) {
        int i = 2 * w + ii;
        int r = 4 * i + rowinA;
        int grow = n0 + r; if (grow >= NN) grow = NN - 1;
        int q = cA ^ (rowinA << 2) ^ (i & 3);
        aoff[ii] = (size_t)grow * KD + (size_t)kc0 + (size_t)(q * 4);
    }
    const size_t amax = (size_t)NN * KD - 4;
    const int rowinW = lane >> 3;
    const int qw = (lane & 7) ^ rowinW;
    size_t woff[4];
    #pragma unroll
    for (int jj = 0; jj < 4; ++jj) {
        int j = 4 * w + jj;
        int r = 8 * j + rowinW;
        woff[jj] = (size_t)r * KP + (size_t)kc0 + (size_t)(qw * 8);
    }

    const int fr = lane & 15, hi = lane >> 4;
    const int ar0 = (w & 1) * 16;
    const int c0w = (w >> 1) * 64;
    const int arow = ar0 + fr;
    const int apage = (arow >> 2) * 256 + (arow & 3) * 64;
    const int asw = ((arow & 3) << 2) ^ ((arow >> 2) & 3);

    f32x4 acc[4] = {};

    auto stage = [&](int s, int b) {
        const int ko = s * KSTEP;
        #pragma unroll
        for (int ii = 0; ii < 2; ++ii) {
            size_t o = aoff[ii] + ko;
            if (o > amax) o = amax;
            gload16(x + o, &AT[b][(2 * w + ii) * 256]);
        }
        #pragma unroll
        for (int jj = 0; jj < 4; ++jj)
            gload16(Wb + woff[jj] + ko, &WT[b][(4 * w + jj) * 512]);
    };

    stage(0, 0);
    __syncthreads();

    for (int s = 0; s < NST; ++s) {
        if (s + 1 < NST) stage(s + 1, (s + 1) & 1);
        const float* ab = &AT[s & 1][0];
        const u16* wbuf = &WT[s & 1][0];
        #pragma unroll
        for (int p = 0; p < 2; ++p) {
            const int q0 = p * 8 + hi * 2;
            f32x4 alo = *(const f32x4*)&ab[apage + ((q0    ) ^ asw) * 4];
            f32x4 ahi = *(const f32x4*)&ab[apage + ((q0 + 1) ^ asw) * 4];
            u16 au[8] = { f2bf(alo[0]), f2bf(alo[1]), f2bf(alo[2]), f2bf(alo[3]),
                          f2bf(ahi[0]), f2bf(ahi[1]), f2bf(ahi[2]), f2bf(ahi[3]) };
            bf16x8 af = *(const bf16x8*)au;
            #pragma unroll
            for (int f = 0; f < 4; ++f) {
                int wrow = c0w + f * 16 + fr;
                int kcw = (p * 4 + hi) ^ (wrow & 7);
                bf16x8 bfr = *(const bf16x8*)&wbuf[(wrow >> 3) * 512 + (wrow & 7) * 64 + kcw * 8];
                acc[f] = __builtin_amdgcn_mfma_f32_16x16x32_bf16(af, bfr, acc[f], 0, 0, 0);
            }
        }
        __syncthreads();
    }

    float* ypb = yp + (size_t)blockIdx.y * NN * 128;
    #pragma unroll
    for (int f = 0; f < 4; ++f) {
        #pragma unroll
        for (int j = 0; j < 4; ++j) {
            int n = n0 + ar0 + hi * 4 + j;
            int col = c0w + f * 16 + fr;
            if (n < NN) ypb[n * 128 + col] = acc[f][j];
        }
    }
}

// ---------- reduce split-K partials: y = yp0 + yp1 ----------
__global__ __launch_bounds__(256) void yreduce_kernel(const float* __restrict__ yp, float* __restrict__ y) {
    int i = blockIdx.x * 256 + threadIdx.x;
    if (i >= NN * 128 / 4) return;
    f32x4u a = ((const f32x4u*)yp)[i];
    f32x4u b = ((const f32x4u*)(yp + (size_t)NN * 128))[i];
    a.x += b.x; a.y += b.y; a.z += b.z; a.w += b.w;
    ((f32x4u*)y)[i] = a;
}

// ---------- CSR gather aggregation: agg[n][d] = sum over in-edges of y[src][d] ----------
// DIM=64: one wave per node, lane = dim. No atomics; full overwrite.
__global__ __launch_bounds__(256) void agg_csr64(const float* __restrict__ y, const int* __restrict__ rowptr,
                                                 const int* __restrict__ csr, float* __restrict__ agg) {
    int n = (blockIdx.x * 256 + threadIdx.x) >> 6;
    int lane = threadIdx.x & 63;
    if (n >= NN) return;
    int beg = rowptr[n], end = rowptr[n + 1];
    float acc = 0.f;
    for (int e = beg; e < end; ++e)
        acc += y[(size_t)csr[e] * 128 + lane];
    agg[n * 64 + lane] = acc;
}

// DIM=32: two edges per iteration (half-wave each), merge via shfl_xor(32).
__global__ __launch_bounds__(256) void agg_csr32(const float* __restrict__ y, const int* __restrict__ rowptr,
                                                 const int* __restrict__ csr, float* __restrict__ agg) {
    int n = (blockIdx.x * 256 + threadIdx.x) >> 6;
    int lane = threadIdx.x & 63;
    if (n >= NN) return;
    int half = lane >> 5, d = lane & 31;
    int beg = rowptr[n], end = rowptr[n + 1];
    float acc = 0.f;
    for (int e = beg + half; e < end; e += 2)
        acc += y[(size_t)csr[e] * 64 + d];
    acc += __shfl_xor(acc, 32);
    if (lane < 32) agg[n * 32 + lane] = acc;
}

// ---------- fused combine + GEMM for layers 2/3 ----------
template<int DIN>
__global__ __launch_bounds__(256) void mm23_fused(const float* __restrict__ agg, const float* __restrict__ yprev,
                                                  const float* __restrict__ deg_inv, const float* __restrict__ b,
                                                  const float* __restrict__ Wl, const float* __restrict__ Wr,
                                                  float* __restrict__ yout) {
    __shared__ float Xs[32][DIN + 1];
    __shared__ float Ws[64][DIN + 1];
    const int t = threadIdx.x;
    const int n0 = blockIdx.x * 32;
    #pragma unroll
    for (int i = 0; i < (64 * DIN) / 256; ++i) {
        int e = t + i * 256;
        int row = e / DIN, col = e % DIN;
        Ws[row][col] = (row < 32) ? Wl[row * DIN + col] : Wr[(row - 32) * DIN + col];
    }
    #pragma unroll
    for (int i = 0; i < (32 * DIN) / 256; ++i) {
        int e = t + i * 256;
        int r = e / DIN, d = e % DIN;
        int n = n0 + r;
        float v = 0.f;
        if (n < NN)
            v = fmaxf(agg[n * DIN + d] * deg_inv[n] + b[d] + yprev[n * 2 * DIN + DIN + d], 0.f);
        Xs[r][d] = v;
    }
    __syncthreads();
    const int tr = t >> 5;
    const int tc = t & 31;
    float acc[4][2] = {};
    #pragma unroll 4
    for (int k = 0; k < DIN; ++k) {
        float xv[4], wv[2];
        #pragma unroll
        for (int r = 0; r < 4; ++r) xv[r] = Xs[tr * 4 + r][k];
        wv[0] = Ws[tc * 2][k];
        wv[1] = Ws[tc * 2 + 1][k];
        #pragma unroll
        for (int r = 0; r < 4; ++r) {
            acc[r][0] = fmaf(xv[r], wv[0], acc[r][0]);
            acc[r][1] = fmaf(xv[r], wv[1], acc[r][1]);
        }
    }
    #pragma unroll
    for (int r = 0; r < 4; ++r) {
        int n = n0 + tr * 4 + r;
        if (n < NN) {
            yout[n * 64 + tc * 2]     = acc[r][0];
            yout[n * 64 + tc * 2 + 1] = acc[r][1];
        }
    }
}

// ---------- fused combine3 + post_mp + log_softmax ----------
__global__ __launch_bounds__(256) void final_fused(const float* __restrict__ agg, const float* __restrict__ y3,
                                                   const float* __restrict__ deg_inv, const float* __restrict__ b3,
                                                   const float* __restrict__ M1w, const float* __restrict__ M1b,
                                                   const float* __restrict__ M2w, const float* __restrict__ M2b,
                                                   float* __restrict__ out) {
    int wv = (blockIdx.x * 256 + threadIdx.x) >> 6;
    int lane = threadIdx.x & 63;
    if (wv >= NN) return;  // uniform per wave
    float hv = 0.f;
    if (lane < 32)
        hv = fmaxf(agg[wv * 32 + lane] * deg_inv[wv] + b3[lane] + y3[wv * 64 + 32 + lane], 0.f);
    float tv = (lane < 32) ? M1b[lane] : 0.f;
    #pragma unroll 8
    for (int k = 0; k < 32; ++k) {
        float hk = __shfl(hv, k, 64);
        if (lane < 32) tv = fmaf(hk, M1w[lane * 32 + k], tv);
    }
    float uv = (lane < 7) ? M2b[lane] : 0.f;
    #pragma unroll 8
    for (int k = 0; k < 32; ++k) {
        float tk = __shfl(tv, k, 64);
        if (lane < 7) uv = fmaf(tk, M2w[lane * 32 + k], uv);
    }
    float m = -1e30f;
    float uc[7];
    #pragma unroll
    for (int c = 0; c < 7; ++c) { uc[c] = __shfl(uv, c, 64); m = fmaxf(m, uc[c]); }
    float s = 0.f;
    #pragma unroll
    for (int c = 0; c < 7; ++c) s += expf(uc[c] - m);
    float lse = m + logf(s);
    if (lane < 7) out[wv * 7 + lane] = uv - lse;
}

extern "C" void kernel_launch(void* const* d_in, const int* in_sizes, int n_in,
                              void* d_out, int out_size, void* d_ws, size_t ws_size,
                              hipStream_t stream) {
    const float* x   = (const float*)d_in[0];
    const int*   eix = (const int*)d_in[1];
    const float* W1l = (const float*)d_in[2];
    const float* b1  = (const float*)d_in[3];
    const float* W1r = (const float*)d_in[4];
    const float* W2l = (const float*)d_in[5];
    const float* b2  = (const float*)d_in[6];
    const float* W2r = (const float*)d_in[7];
    const float* W3l = (const float*)d_in[8];
    const float* b3  = (const float*)d_in[9];
    const float* W3r = (const float*)d_in[10];
    const float* M1w = (const float*)d_in[11];
    const float* M1b = (const float*)d_in[12];
    const float* M2w = (const float*)d_in[13];
    const float* M2b = (const float*)d_in[14];
    float* out = (float*)d_out;

    char* w = (char*)d_ws;
    int*   flag   = (int*)w;    w += 256;
    int*   srcI   = (int*)w;    w += NE * 4;
    int*   dstI   = (int*)w;    w += NE * 4;
    int*   cnt    = (int*)w;    w += 40960;       // zeroed each call
    int*   rowptr = (int*)w;    w += 40964;
    int*   cursor = (int*)w;    w += 40960;
    int*   csr    = (int*)w;    w += NE * 4;
    float* deg    = (float*)w;  w += 40960;       // deg_inv
    float* agg1   = (float*)w;  w += NN * 64 * 4;
    float* agg2   = (float*)w;  w += NN * 32 * 4;
    float* agg3   = (float*)w;  w += NN * 32 * 4;
    float* y      = (float*)w;  w += NN * 128 * 4;
    float* yp     = (float*)w;  w += (size_t)SK1 * NN * 128 * 4;
    float* y2     = (float*)w;  w += NN * 64 * 4;
    float* y3     = (float*)w;  w += NN * 64 * 4;
    u16*   Wb     = (u16*)w;    w += 128 * KP * 2;

    detect_kernel<<<1, 256, 0, stream>>>(eix, flag);
    hipMemsetAsync(cnt, 0, NN * 4, stream);
    repackdeg_kernel<<<(NE + 255) / 256, 256, 0, stream>>>(eix, flag, srcI, dstI, cnt);
    scan_kernel<<<1, 256, 0, stream>>>(cnt, rowptr, cursor, deg);
    scatter_kernel<<<(NE + 255) / 256, 256, 0, stream>>>(srcI, dstI, cursor, csr);

    convw_kernel<<<(128 * (KP / 8) + 255) / 256, 256, 0, stream>>>(W1l, W1r, Wb);

    // layer 1: global_load_lds staging, no atomics
    {
        dim3 grid((NN + 31) / 32, SK1);
        mm1_mfma<<<grid, 256, 0, stream>>>(x, Wb, yp);
    }
    yreduce_kernel<<<(NN * 128 / 4 + 255) / 256, 256, 0, stream>>>(yp, y);
    agg_csr64<<<(NN + 3) / 4, 256, 0, stream>>>(y, rowptr, csr, agg1);

    // layer 2 (combine fused into GEMM staging)
    mm23_fused<64><<<(NN + 31) / 32, 256, 0, stream>>>(agg1, y, deg, b1, W2l, W2r, y2);
    agg_csr32<<<(NN + 3) / 4, 256, 0, stream>>>(y2, rowptr, csr, agg2);

    // layer 3
    mm23_fused<32><<<(NN + 31) / 32, 256, 0, stream>>>(agg2, y2, deg, b2, W3l, W3r, y3);
    agg_csr32<<<(NN + 3) / 4, 256, 0, stream>>>(y3, rowptr, csr, agg3);

    // combine3 + post_mp + log_softmax
    final_fused<<<(NN + 3) / 4, 256, 0, stream>>>(agg3, y3, deg, b3, M1w, M1b, M2w, M2b, out);
}